// Round 11
// baseline (396.440 us; speedup 1.0000x reference)
//
#include <hip/hip_runtime.h>
#include <hip/hip_bf16.h>

#define B_ 8
#define D_ 40
#define T_ 192
#define G_ 256
#define U_ 768   // 3*UNITS
#define H_ 256   // UNITS

__device__ inline float sigmoidf_(float x){
  return 1.0f/(1.0f+__expf(-x));
}
__device__ inline float tanhf_(float x){
  float ax = fabsf(x);
  float e = __expf(-2.0f*ax);
  float t = (1.0f-e)/(1.0f+e);
  return copysignf(t, x);
}
__device__ inline int sdot4(int a, int b, int c){
#if __has_builtin(__builtin_amdgcn_sdot4)
  return __builtin_amdgcn_sdot4(a, b, c, false);
#else
  int r = c;
  #pragma unroll
  for (int i=0;i<4;i++){
    int ai = (a << (24-8*i)) >> 24;
    int bi = (b << (24-8*i)) >> 24;
    r += ai*bi;
  }
  return r;
#endif
}
__device__ inline int pack4(int q0,int q1,int q2,int q3){
  return (q0&255) | ((q1&255)<<8) | ((q2&255)<<16) | ((q3&255)<<24);
}

// ---------------- Kernel 1: single-channel interp + per-(b,d) mean ----------
__global__ __launch_bounds__(256) void k_interp(
    const float* __restrict__ times, const float* __restrict__ values,
    const float* __restrict__ meas, const float* __restrict__ grid,
    const float* __restrict__ ksic,
    float* __restrict__ y, float* __restrict__ w, float* __restrict__ ytr,
    float* __restrict__ mean){
  int bd = blockIdx.x;            // b*D_+d
  int b = bd / D_, d = bd % D_;
  int g = threadIdx.x;
  __shared__ float tt[T_], vv[T_], mm[T_];
  __shared__ float red[256];
  if (g < T_){
    tt[g] = times[bd*T_+g];
    vv[g] = values[bd*T_+g];
    mm[g] = meas[bd*T_+g];
  }
  __syncthreads();
  float alpha = log1pf(__expf(ksic[d]));   // softplus
  float tg = grid[b*G_+g];
  float nmin = 3.4e38f;
  for (int t=0;t<T_;t++){
    if (mm[t] > 0.0f){
      float dd = tt[t]-tg;
      nmin = fminf(nmin, dd*dd);
    }
  }
  float s1=0.f, sv1=0.f, s10=0.f, sv10=0.f;
  for (int t=0;t<T_;t++){
    if (mm[t] > 0.0f){
      float dd = tt[t]-tg;
      float n = dd*dd - nmin;               // >= 0
      float e1  = __expf(-alpha*n);
      float e10 = __expf(-10.0f*alpha*n);
      s1 += e1;  sv1 += e1*vv[t];
      s10 += e10; sv10 += e10*vv[t];
    }
  }
  float yv = sv1/s1;
  float wv = -alpha*nmin + __logf(s1);
  y[bd*G_+g]   = yv;
  w[bd*G_+g]   = wv;
  ytr[bd*G_+g] = sv10/s10;
  red[g] = yv;
  __syncthreads();
  for (int s=128;s>0;s>>=1){
    if (g<s) red[g]+=red[g+s];
    __syncthreads();
  }
  if (g==0) mean[bd] = red[0]*(1.0f/(float)G_);
}

// ---------------- Kernel 2: cross-channel interp + feats + x_proj -----------
__global__ __launch_bounds__(256) void k_cross(
    const float* __restrict__ y, const float* __restrict__ w,
    const float* __restrict__ ytr, const float* __restrict__ mean,
    const float* __restrict__ crossW, const float* __restrict__ Wx,
    const float* __restrict__ gru_b, const int* __restrict__ lens,
    float* __restrict__ xproj){
  int bg = blockIdx.x;              // b*G_+g
  int b = bg >> 8, g = bg & 255;
  if (g >= lens[b]) return;         // x_proj unused beyond length
  __shared__ float wd[D_], yd[D_], ytrd[D_], md[D_], cc[D_], feats[3*D_];
  __shared__ float wstat[2];
  int tid = threadIdx.x;
  if (tid < D_){
    int idx = (b*D_+tid)*G_+g;
    wd[tid]=w[idx]; yd[tid]=y[idx]; ytrd[tid]=ytr[idx]; md[tid]=mean[b*D_+tid];
  }
  __syncthreads();
  if (tid==0){
    float mx=-3.4e38f;
    for (int d2=0;d2<D_;d2++) mx = fmaxf(mx, wd[d2]);
    float s=0.f;
    for (int d2=0;d2<D_;d2++) s += __expf(wd[d2]-mx);
    wstat[0]=mx; wstat[1]=1.0f/s;
  }
  __syncthreads();
  if (tid<D_){
    float sw = __expf(wd[tid]-wstat[0])*wstat[1];
    cc[tid] = sw*(yd[tid]-md[tid]);
  }
  __syncthreads();
  if (tid<D_){
    float acc=0.f;
    for (int d2=0;d2<D_;d2++) acc += cc[d2]*crossW[d2*D_+tid];
    float rep = acc + md[tid];
    feats[tid]       = rep;                   // rep1
    feats[D_+tid]    = __expf(wd[tid]);       // intensity
    feats[2*D_+tid]  = ytrd[tid]-rep;         // y_trans - rep1
  }
  __syncthreads();
  for (int jj=0;jj<3;jj++){
    int j = tid + jj*256;
    float acc = gru_b[j];
    #pragma unroll 4
    for (int i=0;i<3*D_;i++) acc += feats[i]*Wx[i*U_+j];
    xproj[(size_t)bg*U_ + j] = acc;
  }
}

// ---------------- Kernel 3: demo MLP -> h0 ----------------------------------
__global__ __launch_bounds__(256) void k_demo(
    const float* __restrict__ demo, const float* __restrict__ W1,
    const float* __restrict__ b1, const float* __restrict__ W2,
    const float* __restrict__ b2, float* __restrict__ h0){
  __shared__ float dl[B_*16];
  __shared__ float hid[B_*H_];
  int u = threadIdx.x;
  if (u < B_*16) dl[u] = demo[u];
  __syncthreads();
  float acc[B_];
  #pragma unroll
  for (int b=0;b<B_;b++) acc[b]=b1[u];
  for (int i=0;i<16;i++){
    float w1 = W1[i*H_+u];
    #pragma unroll
    for (int b=0;b<B_;b++) acc[b] += dl[b*16+i]*w1;
  }
  #pragma unroll
  for (int b=0;b<B_;b++) hid[b*H_+u] = fmaxf(acc[b],0.f);
  __syncthreads();
  #pragma unroll
  for (int b=0;b<B_;b++) acc[b]=b2[u];
  for (int k=0;k<H_;k++){
    float w2 = W2[k*H_+u];
    #pragma unroll
    for (int b=0;b<B_;b++) acc[b] += hid[b*H_+k]*w2;
  }
  #pragma unroll
  for (int b=0;b<B_;b++) h0[b*H_+u]=acc[b];
}

// ---------------- Kernel 3b: quantize Wh -> int8 packed (parallel) ----------
__global__ __launch_bounds__(256) void k_quant(
    const float* __restrict__ Wh, int* __restrict__ wsq,
    float* __restrict__ wmaxs){
  int c0 = blockIdx.x*64;
  int rg = threadIdx.x >> 6;       // 0..3
  int cc = threadIdx.x & 63;
  int col = c0 + cc;
  float v[64];
  float mx = 0.f;
  #pragma unroll
  for (int r=0;r<64;r++){
    v[r] = Wh[(size_t)(rg*64+r)*U_ + col];
    mx = fmaxf(mx, fabsf(v[r]));
  }
  __shared__ float cm[4][64];
  cm[rg][cc] = mx;
  __syncthreads();
  float m = fmaxf(fmaxf(cm[0][cc],cm[1][cc]), fmaxf(cm[2][cc],cm[3][cc]));
  float iw = (m>0.f)? 127.0f/m : 0.f;
  if (rg==0) wmaxs[col] = m;
  #pragma unroll
  for (int k=0;k<16;k++){
    int q0=(int)rintf(v[4*k+0]*iw), q1=(int)rintf(v[4*k+1]*iw),
        q2=(int)rintf(v[4*k+2]*iw), q3=(int)rintf(v[4*k+3]*iw);
    wsq[(size_t)(rg*16+k)*U_ + col] = pack4(q0,q1,q2,q3);
  }
}

// ---------------- Kernel 4: masked GRU, int8, 2 batches per block -----------
// R8/R9/R10 all plateaued ~850ns/step at wildly different reg outcomes ->
// the floor is LATENCY exposure at 1-2 waves/SIMD, not spill. Fix: give each
// SIMD independent work. 4 blocks x 512 threads; thread (p=t>>8, j=t&255)
// owns rows [128p,128p+128) of int8 cols {z_j,r_j,h_j} (96 dword regs,
// R8-proven fit under the 128-reg grant) and computes dot partials for BOTH
// of the block's batches (6 independent sdot chains; both waves per SIMD
// busy in every phase: p0 gates batch0, p1 gates batch1 -- no idle tail).
// i32 partial exchange via LDS (write slot t, read t^256) is exact.
// Frozen batches (g>=len_b) re-write their stale quantized byte, so the two
// batches' differing lens cost nothing.
__global__ __launch_bounds__(512, 1)
void k_gru(
    const int* __restrict__ wsq, const float* __restrict__ wmaxs,
    const float* __restrict__ gru_b,
    const float* __restrict__ xproj, const float* __restrict__ h0,
    const int* __restrict__ lens, const float* __restrict__ outW,
    const float* __restrict__ outb, float* __restrict__ out){
  int t = threadIdx.x;
  int p = t >> 8;                      // half / batch index (wave-uniform)
  int j = t & 255;                     // hidden unit / column
  int bb = blockIdx.x*2 + p;           // this thread's batch

  __shared__ __align__(16) int hq[2][2][64];  // [batch][buf][64 dwords of i8 h]
  __shared__ int   ispart[3][512];            // i32 partial exchange
  __shared__ float redf[2][256];
  __shared__ float shs2[2][2];                // per-batch [inv_sh, s_h]

  // ---- per-batch h0 abs-max -> fixed h scale ----
  float hj = h0[bb*H_+j];
  redf[p][j] = fabsf(hj);
  int lenA = lens[blockIdx.x*2], lenB = lens[blockIdx.x*2+1];
  int len_max = max(lenA, lenB);
  int mylen = p ? lenB : lenA;
  __syncthreads();
  for (int st=128; st>0; st>>=1){
    if (j < st) redf[p][j] = fmaxf(redf[p][j], redf[p][j+st]);
    __syncthreads();
  }
  if (j==0){
    float bound = fmaxf(redf[p][0], 1.0f);
    shs2[p][0] = 127.0f/bound;
    shs2[p][1] = bound/127.0f;
  }
  __syncthreads();
  float inv_sh = shs2[p][0];
  float s_h    = shs2[p][1];

  // per-column dequant factors (batch-specific via s_h)
  float cm0 = wmaxs[j], cm1 = wmaxs[H_+j], cm2 = wmaxs[2*H_+j];
  float fz = (cm0*(1.0f/127.0f))*s_h;
  float fr = (cm1*(1.0f/127.0f))*s_h;
  float fh = (cm2*(1.0f/127.0f))*s_h;
  float brz = gru_b[U_+j], brr = gru_b[U_+H_+j], brh = gru_b[U_+2*H_+j];

  // ---- load pre-packed weight half-columns (coalesced across j) ----
  int wqz[32], wqr[32], wqh[32];
  #pragma unroll
  for (int k=0;k<32;k++) wqz[k] = wsq[(size_t)(32*p+k)*U_ + j];
  #pragma unroll
  for (int k=0;k<32;k++) wqr[k] = wsq[(size_t)(32*p+k)*U_ + H_ + j];
  #pragma unroll
  for (int k=0;k<32;k++) wqh[k] = wsq[(size_t)(32*p+k)*U_ + 2*H_ + j];

  // quantized h byte for this thread's (batch, unit)
  int qb;
  {
    float qf = fmaxf(-127.f, fminf(127.f, rintf(hj*inv_sh)));
    qb = (int)qf;
    ((signed char*)hq[p][0])[j] = (signed char)qb;
  }
  const float* xbase = xproj + (size_t)bb*G_*U_;
  __syncthreads();

  for (int g=0; g<len_max; g++){
    // x for this thread's batch, this step (in flight during the dot phase)
    float xpz=0.f, xpr=0.f, xph=0.f;
    if (g < mylen){
      const float* xr = xbase + (size_t)g*U_;
      xpz = xr[j]; xpr = xr[H_+j]; xph = xr[2*H_+j];
    }
    // dot partials for BOTH batches over this thread's 128 rows
    const int4* hA = ((const int4*)hq[0][g&1]) + p*8;
    const int4* hB = ((const int4*)hq[1][g&1]) + p*8;
    int az0=0,ar0=0,ah0=0, az1=0,ar1=0,ah1=0;
    #pragma unroll
    for (int c=0;c<8;c++){
      int4 u = hA[c];
      az0=sdot4(u.x,wqz[4*c+0],az0); ar0=sdot4(u.x,wqr[4*c+0],ar0); ah0=sdot4(u.x,wqh[4*c+0],ah0);
      az0=sdot4(u.y,wqz[4*c+1],az0); ar0=sdot4(u.y,wqr[4*c+1],ar0); ah0=sdot4(u.y,wqh[4*c+1],ah0);
      az0=sdot4(u.z,wqz[4*c+2],az0); ar0=sdot4(u.z,wqr[4*c+2],ar0); ah0=sdot4(u.z,wqh[4*c+2],ah0);
      az0=sdot4(u.w,wqz[4*c+3],az0); ar0=sdot4(u.w,wqr[4*c+3],ar0); ah0=sdot4(u.w,wqh[4*c+3],ah0);
      int4 v = hB[c];
      az1=sdot4(v.x,wqz[4*c+0],az1); ar1=sdot4(v.x,wqr[4*c+0],ar1); ah1=sdot4(v.x,wqh[4*c+0],ah1);
      az1=sdot4(v.y,wqz[4*c+1],az1); ar1=sdot4(v.y,wqr[4*c+1],ar1); ah1=sdot4(v.y,wqh[4*c+1],ah1);
      az1=sdot4(v.z,wqz[4*c+2],az1); ar1=sdot4(v.z,wqr[4*c+2],ar1); ah1=sdot4(v.z,wqh[4*c+2],ah1);
      az1=sdot4(v.w,wqz[4*c+3],az1); ar1=sdot4(v.w,wqr[4*c+3],ar1); ah1=sdot4(v.w,wqh[4*c+3],ah1);
      if (c==3) asm volatile("" ::: "memory");   // bound LDS-read hoisting
    }
    // publish OTHER-batch partials at own slot; read partner's at t^256
    ispart[0][t] = p ? az0 : az1;
    ispart[1][t] = p ? ar0 : ar1;
    ispart[2][t] = p ? ah0 : ah1;
    __syncthreads();
    int sz = (p ? az1 : az0) + ispart[0][t^256];
    int sr = (p ? ar1 : ar0) + ispart[1][t^256];
    int sh = (p ? ah1 : ah0) + ispart[2][t^256];
    float z    = sigmoidf_(xpz + brz + fz*(float)sz);
    float r    = sigmoidf_(xpr + brr + fr*(float)sr);
    float cand = tanhf_(xph + r*(brh + fh*(float)sh));
    float hn = z*hj + (1.0f-z)*cand;
    if (g < mylen){
      hj = hn;
      float qf = fmaxf(-127.f, fminf(127.f, rintf(hj*inv_sh)));
      qb = (int)qf;
    }
    ((signed char*)hq[p][(g+1)&1])[j] = (signed char)qb;
    __syncthreads();
  }

  // out[bb] = sigmoid(h . outW + outb), per-batch reduction in parallel
  redf[p][j] = hj*outW[j];
  __syncthreads();
  for (int st=128;st>0;st>>=1){
    if (j<st) redf[p][j] += redf[p][j+st];
    __syncthreads();
  }
  if (j==0) out[bb] = sigmoidf_(redf[p][0]+outb[0]);
}

extern "C" void kernel_launch(void* const* d_in, const int* in_sizes, int n_in,
                              void* d_out, int out_size, void* d_ws, size_t ws_size,
                              hipStream_t stream) {
  const float* demo   = (const float*)d_in[0];
  const float* times  = (const float*)d_in[1];
  const float* values = (const float*)d_in[2];
  const float* meas   = (const float*)d_in[3];
  const float* grid   = (const float*)d_in[4];
  const float* ksic   = (const float*)d_in[5];
  const float* crossW = (const float*)d_in[6];
  const float* dW1    = (const float*)d_in[7];
  const float* db1    = (const float*)d_in[8];
  const float* dW2    = (const float*)d_in[9];
  const float* db2    = (const float*)d_in[10];
  const float* gWx    = (const float*)d_in[11];
  const float* gWh    = (const float*)d_in[12];
  const float* gb     = (const float*)d_in[13];
  const float* outW   = (const float*)d_in[14];
  const float* outb   = (const float*)d_in[15];
  const int*   lens   = (const int*)d_in[16];
  float* out = (float*)d_out;

  float* ws   = (float*)d_ws;
  float* y    = ws;                        // B*D*G
  float* w    = y    + B_*D_*G_;
  float* ytr  = w    + B_*D_*G_;
  float* mean = ytr  + B_*D_*G_;
  float* h0   = mean + B_*D_;
  float* xprj = h0   + B_*H_;              // B*G*768
  int*   wsq  = (int*)(xprj + (size_t)B_*G_*U_);   // 64*768 dwords (192KB)
  float* wmx  = (float*)(wsq + 64*U_);             // 768 floats

  k_interp<<<B_*D_, 256, 0, stream>>>(times, values, meas, grid, ksic, y, w, ytr, mean);
  k_quant <<<12,    256, 0, stream>>>(gWh, wsq, wmx);
  k_demo  <<<1,     256, 0, stream>>>(demo, dW1, db1, dW2, db2, h0);
  k_cross <<<B_*G_, 256, 0, stream>>>(y, w, ytr, mean, crossW, gWx, gb, lens, xprj);
  k_gru   <<<B_/2,  512, 0, stream>>>(wsq, wmx, gb, xprj, h0, lens, outW, outb, out);
}

// Round 12
// 307.036 us; speedup vs baseline: 1.2912x; 1.2912x over previous
//
#include <hip/hip_runtime.h>
#include <hip/hip_bf16.h>

#define B_ 8
#define D_ 40
#define T_ 192
#define G_ 256
#define U_ 768   // 3*UNITS
#define H_ 256   // UNITS

// Keep a value opaque/live in a VGPR (defeats in-loop reload; R10: FETCH halved)
#define PINV(x) asm volatile("" : "+v"(x))

__device__ inline float sigmoidf_(float x){
  return 1.0f/(1.0f+__expf(-x));
}
__device__ inline float tanhf_(float x){
  float ax = fabsf(x);
  float e = __expf(-2.0f*ax);
  float t = (1.0f-e)/(1.0f+e);
  return copysignf(t, x);
}
__device__ inline int sdot4(int a, int b, int c){
#if __has_builtin(__builtin_amdgcn_sdot4)
  return __builtin_amdgcn_sdot4(a, b, c, false);
#else
  int r = c;
  #pragma unroll
  for (int i=0;i<4;i++){
    int ai = (a << (24-8*i)) >> 24;
    int bi = (b << (24-8*i)) >> 24;
    r += ai*bi;
  }
  return r;
#endif
}
__device__ inline int pack4(int q0,int q1,int q2,int q3){
  return (q0&255) | ((q1&255)<<8) | ((q2&255)<<16) | ((q3&255)<<24);
}

// ---------------- Kernel 1: single-channel interp + per-(b,d) mean ----------
__global__ __launch_bounds__(256) void k_interp(
    const float* __restrict__ times, const float* __restrict__ values,
    const float* __restrict__ meas, const float* __restrict__ grid,
    const float* __restrict__ ksic,
    float* __restrict__ y, float* __restrict__ w, float* __restrict__ ytr,
    float* __restrict__ mean){
  int bd = blockIdx.x;            // b*D_+d
  int b = bd / D_, d = bd % D_;
  int g = threadIdx.x;
  __shared__ float tt[T_], vv[T_], mm[T_];
  __shared__ float red[256];
  if (g < T_){
    tt[g] = times[bd*T_+g];
    vv[g] = values[bd*T_+g];
    mm[g] = meas[bd*T_+g];
  }
  __syncthreads();
  float alpha = log1pf(__expf(ksic[d]));   // softplus
  float tg = grid[b*G_+g];
  float nmin = 3.4e38f;
  for (int t=0;t<T_;t++){
    if (mm[t] > 0.0f){
      float dd = tt[t]-tg;
      nmin = fminf(nmin, dd*dd);
    }
  }
  float s1=0.f, sv1=0.f, s10=0.f, sv10=0.f;
  for (int t=0;t<T_;t++){
    if (mm[t] > 0.0f){
      float dd = tt[t]-tg;
      float n = dd*dd - nmin;               // >= 0
      float e1  = __expf(-alpha*n);
      float e10 = __expf(-10.0f*alpha*n);
      s1 += e1;  sv1 += e1*vv[t];
      s10 += e10; sv10 += e10*vv[t];
    }
  }
  float yv = sv1/s1;
  float wv = -alpha*nmin + __logf(s1);
  y[bd*G_+g]   = yv;
  w[bd*G_+g]   = wv;
  ytr[bd*G_+g] = sv10/s10;
  red[g] = yv;
  __syncthreads();
  for (int s=128;s>0;s>>=1){
    if (g<s) red[g]+=red[g+s];
    __syncthreads();
  }
  if (g==0) mean[bd] = red[0]*(1.0f/(float)G_);
}

// ---------------- Kernel 2: cross-channel interp + feats + x_proj -----------
__global__ __launch_bounds__(256) void k_cross(
    const float* __restrict__ y, const float* __restrict__ w,
    const float* __restrict__ ytr, const float* __restrict__ mean,
    const float* __restrict__ crossW, const float* __restrict__ Wx,
    const float* __restrict__ gru_b, const int* __restrict__ lens,
    float* __restrict__ xproj){
  int bg = blockIdx.x;              // b*G_+g
  int b = bg >> 8, g = bg & 255;
  if (g >= lens[b]) return;         // x_proj unused beyond length
  __shared__ float wd[D_], yd[D_], ytrd[D_], md[D_], cc[D_], feats[3*D_];
  __shared__ float wstat[2];
  int tid = threadIdx.x;
  if (tid < D_){
    int idx = (b*D_+tid)*G_+g;
    wd[tid]=w[idx]; yd[tid]=y[idx]; ytrd[tid]=ytr[idx]; md[tid]=mean[b*D_+tid];
  }
  __syncthreads();
  if (tid==0){
    float mx=-3.4e38f;
    for (int d2=0;d2<D_;d2++) mx = fmaxf(mx, wd[d2]);
    float s=0.f;
    for (int d2=0;d2<D_;d2++) s += __expf(wd[d2]-mx);
    wstat[0]=mx; wstat[1]=1.0f/s;
  }
  __syncthreads();
  if (tid<D_){
    float sw = __expf(wd[tid]-wstat[0])*wstat[1];
    cc[tid] = sw*(yd[tid]-md[tid]);
  }
  __syncthreads();
  if (tid<D_){
    float acc=0.f;
    for (int d2=0;d2<D_;d2++) acc += cc[d2]*crossW[d2*D_+tid];
    float rep = acc + md[tid];
    feats[tid]       = rep;                   // rep1
    feats[D_+tid]    = __expf(wd[tid]);       // intensity
    feats[2*D_+tid]  = ytrd[tid]-rep;         // y_trans - rep1
  }
  __syncthreads();
  for (int jj=0;jj<3;jj++){
    int j = tid + jj*256;
    float acc = gru_b[j];
    #pragma unroll 4
    for (int i=0;i<3*D_;i++) acc += feats[i]*Wx[i*U_+j];
    xproj[(size_t)bg*U_ + j] = acc;
  }
}

// ---------------- Kernel 3: demo MLP -> h0 ----------------------------------
__global__ __launch_bounds__(256) void k_demo(
    const float* __restrict__ demo, const float* __restrict__ W1,
    const float* __restrict__ b1, const float* __restrict__ W2,
    const float* __restrict__ b2, float* __restrict__ h0){
  __shared__ float dl[B_*16];
  __shared__ float hid[B_*H_];
  int u = threadIdx.x;
  if (u < B_*16) dl[u] = demo[u];
  __syncthreads();
  float acc[B_];
  #pragma unroll
  for (int b=0;b<B_;b++) acc[b]=b1[u];
  for (int i=0;i<16;i++){
    float w1 = W1[i*H_+u];
    #pragma unroll
    for (int b=0;b<B_;b++) acc[b] += dl[b*16+i]*w1;
  }
  #pragma unroll
  for (int b=0;b<B_;b++) hid[b*H_+u] = fmaxf(acc[b],0.f);
  __syncthreads();
  #pragma unroll
  for (int b=0;b<B_;b++) acc[b]=b2[u];
  for (int k=0;k<H_;k++){
    float w2 = W2[k*H_+u];
    #pragma unroll
    for (int b=0;b<B_;b++) acc[b] += hid[b*H_+k]*w2;
  }
  #pragma unroll
  for (int b=0;b<B_;b++) h0[b*H_+u]=acc[b];
}

// ---------------- Kernel 3b: quantize Wh -> int8 packed (parallel) ----------
__global__ __launch_bounds__(256) void k_quant(
    const float* __restrict__ Wh, int* __restrict__ wsq,
    float* __restrict__ wmaxs){
  int c0 = blockIdx.x*64;
  int rg = threadIdx.x >> 6;       // 0..3
  int cc = threadIdx.x & 63;
  int col = c0 + cc;
  float v[64];
  float mx = 0.f;
  #pragma unroll
  for (int r=0;r<64;r++){
    v[r] = Wh[(size_t)(rg*64+r)*U_ + col];
    mx = fmaxf(mx, fabsf(v[r]));
  }
  __shared__ float cm[4][64];
  cm[rg][cc] = mx;
  __syncthreads();
  float m = fmaxf(fmaxf(cm[0][cc],cm[1][cc]), fmaxf(cm[2][cc],cm[3][cc]));
  float iw = (m>0.f)? 127.0f/m : 0.f;
  if (rg==0) wmaxs[col] = m;
  #pragma unroll
  for (int k=0;k<16;k++){
    int q0=(int)rintf(v[4*k+0]*iw), q1=(int)rintf(v[4*k+1]*iw),
        q2=(int)rintf(v[4*k+2]*iw), q3=(int)rintf(v[4*k+3]*iw);
    wsq[(size_t)(rg*16+k)*U_ + col] = pack4(q0,q1,q2,q3);
  }
}

// ---------------- Kernel 4: masked GRU, int8, full-column ownership ---------
// R10 base (best: 844ns/step) + two latency fixes targeting the measured
// ~60% stall budget (active-CU VALUBusy ~39%):
//  (1) chain-split: 12 accumulators (3 gates x 4 sub-chains of 16 sdot4)
//      -> dependent-chain exposure 64*6 -> 16*6 cyc, hidden under issue.
//  (2) 2-deep xproj prefetch: x(g),x(g+1) in regs, issue x(g+2) at top of
//      step g -> ~2 dot-phases (>1200cyc) of cover vs ~900cyc HBM latency.
// 256 threads, one block per batch; weights pinned (R10: halved FETCH).
__global__ __attribute__((amdgpu_flat_work_group_size(256,256), amdgpu_waves_per_eu(1,1)))
void k_gru(
    const int* __restrict__ wsq, const float* __restrict__ wmaxs,
    const float* __restrict__ gru_b,
    const float* __restrict__ xproj, const float* __restrict__ h0,
    const int* __restrict__ lens, const float* __restrict__ outW,
    const float* __restrict__ outb, float* __restrict__ out){
  int b = blockIdx.x;
  int j = threadIdx.x;

  __shared__ __align__(16) int hq[2][64];   // packed i8 h, double-buffered
  __shared__ float red[H_];
  __shared__ float shs[2];                  // [0]=inv_sh, [1]=s_h

  // ---- h0 + abs-max (fixed h scale; |h_new| <= max(|h_old|,1)) ----
  float hj = h0[b*H_+j];
  red[j] = fabsf(hj);
  __syncthreads();
  for (int st=128; st>0; st>>=1){
    if (j < st) red[j] = fmaxf(red[j], red[j+st]);
    __syncthreads();
  }
  if (j==0){
    float bound = fmaxf(red[0], 1.0f);
    shs[0] = 127.0f/bound;
    shs[1] = bound/127.0f;
  }
  __syncthreads();
  float inv_sh = shs[0];
  float s_h    = shs[1];

  // per-column dequant factors
  float cm0 = wmaxs[j], cm1 = wmaxs[H_+j], cm2 = wmaxs[2*H_+j];
  float fz = (cm0*(1.0f/127.0f))*s_h;
  float fr = (cm1*(1.0f/127.0f))*s_h;
  float fh = (cm2*(1.0f/127.0f))*s_h;
  float brz = gru_b[U_+j], brr = gru_b[U_+H_+j], brh = gru_b[U_+2*H_+j];

  // ---- load pre-packed weights (coalesced across j) and PIN in VGPRs ----
  int wqz[64], wqr[64], wqh[64];
  #pragma unroll
  for (int k=0;k<64;k++){ wqz[k] = wsq[(size_t)k*U_ + j];        PINV(wqz[k]); }
  #pragma unroll
  for (int k=0;k<64;k++){ wqr[k] = wsq[(size_t)k*U_ + H_ + j];   PINV(wqr[k]); }
  #pragma unroll
  for (int k=0;k<64;k++){ wqh[k] = wsq[(size_t)k*U_ + 2*H_ + j]; PINV(wqh[k]); }

  {
    float qf = fmaxf(-127.f, fminf(127.f, rintf(hj*inv_sh)));
    ((signed char*)hq[0])[j] = (signed char)(int)qf;
  }
  int len = lens[b];
  const float* xbase = xproj + (size_t)b*G_*U_;
  // 2-deep x prefetch pipeline: x0 = x(g), x1 = x(g+1)
  float x0z = xbase[j], x0r = xbase[H_+j], x0h = xbase[2*H_+j];
  float x1z=0.f, x1r=0.f, x1h=0.f;
  if (len > 1){
    const float* xn = xbase + U_;
    x1z = xn[j]; x1r = xn[H_+j]; x1h = xn[2*H_+j];
  }
  __syncthreads();

  for (int g=0; g<len; g++){
    // issue x(g+2) loads now; consumed two dot-phases later
    float x2z=0.f, x2r=0.f, x2h=0.f;
    if (g+2 < len){
      const float* xn = xbase + (size_t)(g+2)*U_;
      x2z = xn[j]; x2r = xn[H_+j]; x2h = xn[2*H_+j];
    }
    const int4* hc = (const int4*)hq[g&1];
    // 12 accumulators: 3 gates x 4 sub-chains (16 sdot4 deep each)
    int az0=0,az1=0,az2=0,az3=0;
    int ar0=0,ar1=0,ar2=0,ar3=0;
    int ah0=0,ah1=0,ah2=0,ah3=0;
    #pragma unroll
    for (int c=0;c<4;c++){
      int4 hv = hc[c];
      az0=sdot4(hv.x,wqz[4*c+0],az0); ar0=sdot4(hv.x,wqr[4*c+0],ar0); ah0=sdot4(hv.x,wqh[4*c+0],ah0);
      az0=sdot4(hv.y,wqz[4*c+1],az0); ar0=sdot4(hv.y,wqr[4*c+1],ar0); ah0=sdot4(hv.y,wqh[4*c+1],ah0);
      az0=sdot4(hv.z,wqz[4*c+2],az0); ar0=sdot4(hv.z,wqr[4*c+2],ar0); ah0=sdot4(hv.z,wqh[4*c+2],ah0);
      az0=sdot4(hv.w,wqz[4*c+3],az0); ar0=sdot4(hv.w,wqr[4*c+3],ar0); ah0=sdot4(hv.w,wqh[4*c+3],ah0);
    }
    #pragma unroll
    for (int c=4;c<8;c++){
      int4 hv = hc[c];
      az1=sdot4(hv.x,wqz[4*c+0],az1); ar1=sdot4(hv.x,wqr[4*c+0],ar1); ah1=sdot4(hv.x,wqh[4*c+0],ah1);
      az1=sdot4(hv.y,wqz[4*c+1],az1); ar1=sdot4(hv.y,wqr[4*c+1],ar1); ah1=sdot4(hv.y,wqh[4*c+1],ah1);
      az1=sdot4(hv.z,wqz[4*c+2],az1); ar1=sdot4(hv.z,wqr[4*c+2],ar1); ah1=sdot4(hv.z,wqh[4*c+2],ah1);
      az1=sdot4(hv.w,wqz[4*c+3],az1); ar1=sdot4(hv.w,wqr[4*c+3],ar1); ah1=sdot4(hv.w,wqh[4*c+3],ah1);
    }
    #pragma unroll
    for (int c=8;c<12;c++){
      int4 hv = hc[c];
      az2=sdot4(hv.x,wqz[4*c+0],az2); ar2=sdot4(hv.x,wqr[4*c+0],ar2); ah2=sdot4(hv.x,wqh[4*c+0],ah2);
      az2=sdot4(hv.y,wqz[4*c+1],az2); ar2=sdot4(hv.y,wqr[4*c+1],ar2); ah2=sdot4(hv.y,wqh[4*c+1],ah2);
      az2=sdot4(hv.z,wqz[4*c+2],az2); ar2=sdot4(hv.z,wqr[4*c+2],ar2); ah2=sdot4(hv.z,wqh[4*c+2],ah2);
      az2=sdot4(hv.w,wqz[4*c+3],az2); ar2=sdot4(hv.w,wqr[4*c+3],ar2); ah2=sdot4(hv.w,wqh[4*c+3],ah2);
    }
    #pragma unroll
    for (int c=12;c<16;c++){
      int4 hv = hc[c];
      az3=sdot4(hv.x,wqz[4*c+0],az3); ar3=sdot4(hv.x,wqr[4*c+0],ar3); ah3=sdot4(hv.x,wqh[4*c+0],ah3);
      az3=sdot4(hv.y,wqz[4*c+1],az3); ar3=sdot4(hv.y,wqr[4*c+1],ar3); ah3=sdot4(hv.y,wqh[4*c+1],ah3);
      az3=sdot4(hv.z,wqz[4*c+2],az3); ar3=sdot4(hv.z,wqr[4*c+2],ar3); ah3=sdot4(hv.z,wqh[4*c+2],ah3);
      az3=sdot4(hv.w,wqz[4*c+3],az3); ar3=sdot4(hv.w,wqr[4*c+3],ar3); ah3=sdot4(hv.w,wqh[4*c+3],ah3);
    }
    int az = (az0+az1)+(az2+az3);
    int ar = (ar0+ar1)+(ar2+ar3);
    int ah = (ah0+ah1)+(ah2+ah3);
    float z    = sigmoidf_(x0z + brz + fz*(float)az);
    float r    = sigmoidf_(x0r + brr + fr*(float)ar);
    float cand = tanhf_(x0h + r*(brh + fh*(float)ah));
    hj = z*hj + (1.0f-z)*cand;
    float qf = fmaxf(-127.f, fminf(127.f, rintf(hj*inv_sh)));
    ((signed char*)hq[(g+1)&1])[j] = (signed char)(int)qf;
    __syncthreads();                 // single barrier per step
    x0z = x1z; x0r = x1r; x0h = x1h;
    x1z = x2z; x1r = x2r; x1h = x2h;
  }

  // out = sigmoid(h . outW + outb)
  red[j] = hj*outW[j];
  __syncthreads();
  for (int st=128;st>0;st>>=1){
    if (j<st) red[j]+=red[j+st];
    __syncthreads();
  }
  if (j==0) out[b] = sigmoidf_(red[0]+outb[0]);
}

extern "C" void kernel_launch(void* const* d_in, const int* in_sizes, int n_in,
                              void* d_out, int out_size, void* d_ws, size_t ws_size,
                              hipStream_t stream) {
  const float* demo   = (const float*)d_in[0];
  const float* times  = (const float*)d_in[1];
  const float* values = (const float*)d_in[2];
  const float* meas   = (const float*)d_in[3];
  const float* grid   = (const float*)d_in[4];
  const float* ksic   = (const float*)d_in[5];
  const float* crossW = (const float*)d_in[6];
  const float* dW1    = (const float*)d_in[7];
  const float* db1    = (const float*)d_in[8];
  const float* dW2    = (const float*)d_in[9];
  const float* db2    = (const float*)d_in[10];
  const float* gWx    = (const float*)d_in[11];
  const float* gWh    = (const float*)d_in[12];
  const float* gb     = (const float*)d_in[13];
  const float* outW   = (const float*)d_in[14];
  const float* outb   = (const float*)d_in[15];
  const int*   lens   = (const int*)d_in[16];
  float* out = (float*)d_out;

  float* ws   = (float*)d_ws;
  float* y    = ws;                        // B*D*G
  float* w    = y    + B_*D_*G_;
  float* ytr  = w    + B_*D_*G_;
  float* mean = ytr  + B_*D_*G_;
  float* h0   = mean + B_*D_;
  float* xprj = h0   + B_*H_;              // B*G*768
  int*   wsq  = (int*)(xprj + (size_t)B_*G_*U_);   // 64*768 dwords (192KB)
  float* wmx  = (float*)(wsq + 64*U_);             // 768 floats

  k_interp<<<B_*D_, 256, 0, stream>>>(times, values, meas, grid, ksic, y, w, ytr, mean);
  k_quant <<<12,    256, 0, stream>>>(gWh, wsq, wmx);
  k_demo  <<<1,     256, 0, stream>>>(demo, dW1, db1, dW2, db2, h0);
  k_cross <<<B_*G_, 256, 0, stream>>>(y, w, ytr, mean, crossW, gWx, gb, lens, xprj);
  k_gru   <<<B_,    256, 0, stream>>>(wsq, wmx, gb, xprj, h0, lens, outW, outb, out);
}

// Round 13
// 283.601 us; speedup vs baseline: 1.3979x; 1.0826x over previous
//
#include <hip/hip_runtime.h>
#include <hip/hip_bf16.h>

#define B_ 8
#define D_ 40
#define T_ 192
#define G_ 256
#define U_ 768   // 3*UNITS
#define H_ 256   // UNITS

// Keep a value opaque/live in a VGPR (defeats in-loop reload; R10: FETCH halved)
#define PINV(x) asm volatile("" : "+v"(x))

__device__ inline float sigmoidf_(float x){
  return 1.0f/(1.0f+__expf(-x));
}
__device__ inline float tanhf_(float x){
  float ax = fabsf(x);
  float e = __expf(-2.0f*ax);
  float t = (1.0f-e)/(1.0f+e);
  return copysignf(t, x);
}
__device__ inline int sdot4(int a, int b, int c){
#if __has_builtin(__builtin_amdgcn_sdot4)
  return __builtin_amdgcn_sdot4(a, b, c, false);
#else
  int r = c;
  #pragma unroll
  for (int i=0;i<4;i++){
    int ai = (a << (24-8*i)) >> 24;
    int bi = (b << (24-8*i)) >> 24;
    r += ai*bi;
  }
  return r;
#endif
}
__device__ inline int pack4(int q0,int q1,int q2,int q3){
  return (q0&255) | ((q1&255)<<8) | ((q2&255)<<16) | ((q3&255)<<24);
}

// ---------------- Kernel 1: single-channel interp + per-(b,d) mean ----------
__global__ __launch_bounds__(256) void k_interp(
    const float* __restrict__ times, const float* __restrict__ values,
    const float* __restrict__ meas, const float* __restrict__ grid,
    const float* __restrict__ ksic,
    float* __restrict__ y, float* __restrict__ w, float* __restrict__ ytr,
    float* __restrict__ mean){
  int bd = blockIdx.x;            // b*D_+d
  int b = bd / D_, d = bd % D_;
  int g = threadIdx.x;
  __shared__ float tt[T_], vv[T_], mm[T_];
  __shared__ float red[256];
  if (g < T_){
    tt[g] = times[bd*T_+g];
    vv[g] = values[bd*T_+g];
    mm[g] = meas[bd*T_+g];
  }
  __syncthreads();
  float alpha = log1pf(__expf(ksic[d]));   // softplus
  float tg = grid[b*G_+g];
  float nmin = 3.4e38f;
  for (int t=0;t<T_;t++){
    if (mm[t] > 0.0f){
      float dd = tt[t]-tg;
      nmin = fminf(nmin, dd*dd);
    }
  }
  float s1=0.f, sv1=0.f, s10=0.f, sv10=0.f;
  for (int t=0;t<T_;t++){
    if (mm[t] > 0.0f){
      float dd = tt[t]-tg;
      float n = dd*dd - nmin;               // >= 0
      float e1  = __expf(-alpha*n);
      float e10 = __expf(-10.0f*alpha*n);
      s1 += e1;  sv1 += e1*vv[t];
      s10 += e10; sv10 += e10*vv[t];
    }
  }
  float yv = sv1/s1;
  float wv = -alpha*nmin + __logf(s1);
  y[bd*G_+g]   = yv;
  w[bd*G_+g]   = wv;
  ytr[bd*G_+g] = sv10/s10;
  red[g] = yv;
  __syncthreads();
  for (int s=128;s>0;s>>=1){
    if (g<s) red[g]+=red[g+s];
    __syncthreads();
  }
  if (g==0) mean[bd] = red[0]*(1.0f/(float)G_);
}

// ------- Kernel 2: cross-channel interp + feats + x_proj (4 g per block) ----
// Wx is the dominant L2/L3 traffic (was 2048 blocks x 368KB = 754MB). Each
// block now serves 4 grid points: every Wx element loaded once feeds 4
// accumulators -> traffic /4 (188MB). Softmaxes parallel across 4 threads.
__global__ __launch_bounds__(256) void k_cross(
    const float* __restrict__ y, const float* __restrict__ w,
    const float* __restrict__ ytr, const float* __restrict__ mean,
    const float* __restrict__ crossW, const float* __restrict__ Wx,
    const float* __restrict__ gru_b, const int* __restrict__ lens,
    float* __restrict__ xproj){
  int blk = blockIdx.x;             // b*64 + gq
  int b = blk >> 6, gq = blk & 63;
  int g0 = gq*4;
  if (g0 >= lens[b]) return;        // whole quad unused
  __shared__ float wd[4][D_], yd[4][D_], ytrd[4][D_], md[D_];
  __shared__ float cc4[4][D_], feats[4][3*D_];
  __shared__ float wstat[4][2];
  int tid = threadIdx.x;
  int gg = tid / D_;                // valid for tid < 160
  int d  = tid % D_;
  if (tid < 4*D_){
    int idx = (b*D_+d)*G_ + g0 + gg;
    wd[gg][d]=w[idx]; yd[gg][d]=y[idx]; ytrd[gg][d]=ytr[idx];
  }
  if (tid < D_) md[tid] = mean[b*D_+tid];
  __syncthreads();
  if (tid < 4){                     // 4 parallel softmax scans
    float mx=-3.4e38f;
    for (int d2=0;d2<D_;d2++) mx = fmaxf(mx, wd[tid][d2]);
    float s=0.f;
    for (int d2=0;d2<D_;d2++) s += __expf(wd[tid][d2]-mx);
    wstat[tid][0]=mx; wstat[tid][1]=1.0f/s;
  }
  __syncthreads();
  if (tid < 4*D_){
    float sw = __expf(wd[gg][d]-wstat[gg][0])*wstat[gg][1];
    cc4[gg][d] = sw*(yd[gg][d]-md[d]);
  }
  __syncthreads();
  if (tid < 4*D_){
    float acc=0.f;
    for (int d2=0;d2<D_;d2++) acc += cc4[gg][d2]*crossW[d2*D_+d];
    float rep = acc + md[d];
    feats[gg][d]       = rep;                    // rep1
    feats[gg][D_+d]    = __expf(wd[gg][d]);      // intensity
    feats[gg][2*D_+d]  = ytrd[gg][d]-rep;        // y_trans - rep1
  }
  __syncthreads();
  for (int jj=0;jj<3;jj++){
    int j = tid + jj*256;
    float bi = gru_b[j];
    float a0=bi, a1=bi, a2=bi, a3=bi;
    #pragma unroll 4
    for (int i=0;i<3*D_;i++){
      float wv = Wx[i*U_+j];        // one load feeds 4 g's
      a0 += feats[0][i]*wv;
      a1 += feats[1][i]*wv;
      a2 += feats[2][i]*wv;
      a3 += feats[3][i]*wv;
    }
    size_t base = ((size_t)(b*G_+g0))*U_ + j;
    xproj[base]       = a0;         // g >= len slots written but never read
    xproj[base+U_]    = a1;
    xproj[base+2*U_]  = a2;
    xproj[base+3*U_]  = a3;
  }
}

// ---------------- Kernel 3: demo MLP -> h0 ----------------------------------
__global__ __launch_bounds__(256) void k_demo(
    const float* __restrict__ demo, const float* __restrict__ W1,
    const float* __restrict__ b1, const float* __restrict__ W2,
    const float* __restrict__ b2, float* __restrict__ h0){
  __shared__ float dl[B_*16];
  __shared__ float hid[B_*H_];
  int u = threadIdx.x;
  if (u < B_*16) dl[u] = demo[u];
  __syncthreads();
  float acc[B_];
  #pragma unroll
  for (int b=0;b<B_;b++) acc[b]=b1[u];
  for (int i=0;i<16;i++){
    float w1 = W1[i*H_+u];
    #pragma unroll
    for (int b=0;b<B_;b++) acc[b] += dl[b*16+i]*w1;
  }
  #pragma unroll
  for (int b=0;b<B_;b++) hid[b*H_+u] = fmaxf(acc[b],0.f);
  __syncthreads();
  #pragma unroll
  for (int b=0;b<B_;b++) acc[b]=b2[u];
  for (int k=0;k<H_;k++){
    float w2 = W2[k*H_+u];
    #pragma unroll
    for (int b=0;b<B_;b++) acc[b] += hid[b*H_+k]*w2;
  }
  #pragma unroll
  for (int b=0;b<B_;b++) h0[b*H_+u]=acc[b];
}

// ---------------- Kernel 3b: quantize Wh -> int8 packed (parallel) ----------
__global__ __launch_bounds__(256) void k_quant(
    const float* __restrict__ Wh, int* __restrict__ wsq,
    float* __restrict__ wmaxs){
  int c0 = blockIdx.x*64;
  int rg = threadIdx.x >> 6;       // 0..3
  int cc = threadIdx.x & 63;
  int col = c0 + cc;
  float v[64];
  float mx = 0.f;
  #pragma unroll
  for (int r=0;r<64;r++){
    v[r] = Wh[(size_t)(rg*64+r)*U_ + col];
    mx = fmaxf(mx, fabsf(v[r]));
  }
  __shared__ float cm[4][64];
  cm[rg][cc] = mx;
  __syncthreads();
  float m = fmaxf(fmaxf(cm[0][cc],cm[1][cc]), fmaxf(cm[2][cc],cm[3][cc]));
  float iw = (m>0.f)? 127.0f/m : 0.f;
  if (rg==0) wmaxs[col] = m;
  #pragma unroll
  for (int k=0;k<16;k++){
    int q0=(int)rintf(v[4*k+0]*iw), q1=(int)rintf(v[4*k+1]*iw),
        q2=(int)rintf(v[4*k+2]*iw), q3=(int)rintf(v[4*k+3]*iw);
    wsq[(size_t)(rg*16+k)*U_ + col] = pack4(q0,q1,q2,q3);
  }
}

// ---------------- Kernel 4: masked GRU, int8 (exact R10 body - best) --------
// R10 = 844ns/step, best of R8-R12. Weights pinned (live in VGPR/AGPR, no
// in-loop reload -> FETCH halved); 3 accumulator chains; 1-deep x prefetch;
// single barrier per step. R11/R12 structural variants all regressed; this
// design is locally converged (floor = single-wave latency exposure).
__global__ __attribute__((amdgpu_flat_work_group_size(256,256), amdgpu_waves_per_eu(1,1)))
void k_gru(
    const int* __restrict__ wsq, const float* __restrict__ wmaxs,
    const float* __restrict__ gru_b,
    const float* __restrict__ xproj, const float* __restrict__ h0,
    const int* __restrict__ lens, const float* __restrict__ outW,
    const float* __restrict__ outb, float* __restrict__ out){
  int b = blockIdx.x;
  int j = threadIdx.x;

  __shared__ __align__(16) int hq[2][64];   // packed i8 h, double-buffered
  __shared__ float red[H_];
  __shared__ float shs[2];                  // [0]=inv_sh, [1]=s_h

  // ---- h0 + abs-max (fixed h scale; |h_new| <= max(|h_old|,1)) ----
  float hj = h0[b*H_+j];
  red[j] = fabsf(hj);
  __syncthreads();
  for (int st=128; st>0; st>>=1){
    if (j < st) red[j] = fmaxf(red[j], red[j+st]);
    __syncthreads();
  }
  if (j==0){
    float bound = fmaxf(red[0], 1.0f);
    shs[0] = 127.0f/bound;
    shs[1] = bound/127.0f;
  }
  __syncthreads();
  float inv_sh = shs[0];
  float s_h    = shs[1];

  // per-column dequant factors
  float cm0 = wmaxs[j], cm1 = wmaxs[H_+j], cm2 = wmaxs[2*H_+j];
  float fz = (cm0*(1.0f/127.0f))*s_h;
  float fr = (cm1*(1.0f/127.0f))*s_h;
  float fh = (cm2*(1.0f/127.0f))*s_h;
  float brz = gru_b[U_+j], brr = gru_b[U_+H_+j], brh = gru_b[U_+2*H_+j];

  // ---- load pre-packed weights (coalesced across j) and PIN in VGPRs ----
  int wqz[64], wqr[64], wqh[64];
  #pragma unroll
  for (int k=0;k<64;k++){ wqz[k] = wsq[(size_t)k*U_ + j];        PINV(wqz[k]); }
  #pragma unroll
  for (int k=0;k<64;k++){ wqr[k] = wsq[(size_t)k*U_ + H_ + j];   PINV(wqr[k]); }
  #pragma unroll
  for (int k=0;k<64;k++){ wqh[k] = wsq[(size_t)k*U_ + 2*H_ + j]; PINV(wqh[k]); }

  {
    float qf = fmaxf(-127.f, fminf(127.f, rintf(hj*inv_sh)));
    ((signed char*)hq[0])[j] = (signed char)(int)qf;
  }
  int len = lens[b];
  const float* xbase = xproj + (size_t)b*G_*U_;
  float xpz = xbase[j], xpr = xbase[H_+j], xph = xbase[2*H_+j];
  __syncthreads();

  for (int g=0; g<len; g++){
    // prefetch next step's x (consumed next iteration; hides HBM latency)
    float nxz=0.f, nxr=0.f, nxh=0.f;
    if (g+1 < len){
      const float* xn = xbase + (size_t)(g+1)*U_;
      nxz = xn[j]; nxr = xn[H_+j]; nxh = xn[2*H_+j];
    }
    const int4* hc = (const int4*)hq[g&1];
    int az=0, ar=0, ah=0;
    #pragma unroll
    for (int c=0;c<16;c++){
      int4 hv = hc[c];                              // broadcast ds_read_b128
      az=sdot4(hv.x,wqz[4*c+0],az); ar=sdot4(hv.x,wqr[4*c+0],ar); ah=sdot4(hv.x,wqh[4*c+0],ah);
      az=sdot4(hv.y,wqz[4*c+1],az); ar=sdot4(hv.y,wqr[4*c+1],ar); ah=sdot4(hv.y,wqh[4*c+1],ah);
      az=sdot4(hv.z,wqz[4*c+2],az); ar=sdot4(hv.z,wqr[4*c+2],ar); ah=sdot4(hv.z,wqh[4*c+2],ah);
      az=sdot4(hv.w,wqz[4*c+3],az); ar=sdot4(hv.w,wqr[4*c+3],ar); ah=sdot4(hv.w,wqh[4*c+3],ah);
    }
    float z    = sigmoidf_(xpz + brz + fz*(float)az);
    float r    = sigmoidf_(xpr + brr + fr*(float)ar);
    float cand = tanhf_(xph + r*(brh + fh*(float)ah));
    hj = z*hj + (1.0f-z)*cand;
    float qf = fmaxf(-127.f, fminf(127.f, rintf(hj*inv_sh)));
    ((signed char*)hq[(g+1)&1])[j] = (signed char)(int)qf;
    __syncthreads();                 // single barrier per step
    xpz = nxz; xpr = nxr; xph = nxh;
  }

  // out = sigmoid(h . outW + outb)
  red[j] = hj*outW[j];
  __syncthreads();
  for (int st=128;st>0;st>>=1){
    if (j<st) red[j]+=red[j+st];
    __syncthreads();
  }
  if (j==0) out[b] = sigmoidf_(red[0]+outb[0]);
}

extern "C" void kernel_launch(void* const* d_in, const int* in_sizes, int n_in,
                              void* d_out, int out_size, void* d_ws, size_t ws_size,
                              hipStream_t stream) {
  const float* demo   = (const float*)d_in[0];
  const float* times  = (const float*)d_in[1];
  const float* values = (const float*)d_in[2];
  const float* meas   = (const float*)d_in[3];
  const float* grid   = (const float*)d_in[4];
  const float* ksic   = (const float*)d_in[5];
  const float* crossW = (const float*)d_in[6];
  const float* dW1    = (const float*)d_in[7];
  const float* db1    = (const float*)d_in[8];
  const float* dW2    = (const float*)d_in[9];
  const float* db2    = (const float*)d_in[10];
  const float* gWx    = (const float*)d_in[11];
  const float* gWh    = (const float*)d_in[12];
  const float* gb     = (const float*)d_in[13];
  const float* outW   = (const float*)d_in[14];
  const float* outb   = (const float*)d_in[15];
  const int*   lens   = (const int*)d_in[16];
  float* out = (float*)d_out;

  float* ws   = (float*)d_ws;
  float* y    = ws;                        // B*D*G
  float* w    = y    + B_*D_*G_;
  float* ytr  = w    + B_*D_*G_;
  float* mean = ytr  + B_*D_*G_;
  float* h0   = mean + B_*D_;
  float* xprj = h0   + B_*H_;              // B*G*768
  int*   wsq  = (int*)(xprj + (size_t)B_*G_*U_);   // 64*768 dwords (192KB)
  float* wmx  = (float*)(wsq + 64*U_);             // 768 floats

  k_interp<<<B_*D_, 256, 0, stream>>>(times, values, meas, grid, ksic, y, w, ytr, mean);
  k_quant <<<12,    256, 0, stream>>>(gWh, wsq, wmx);
  k_demo  <<<1,     256, 0, stream>>>(demo, dW1, db1, dW2, db2, h0);
  k_cross <<<B_*64, 256, 0, stream>>>(y, w, ytr, mean, crossW, gWx, gb, lens, xprj);
  k_gru   <<<B_,    256, 0, stream>>>(wsq, wmx, gb, xprj, h0, lens, outW, outb, out);
}